// Round 8
// baseline (113.549 us; speedup 1.0000x reference)
//
#include <hip/hip_runtime.h>
#include <math.h>

#define N_SPK 512
#define N_UTT 32
#define DIM   512
#define EPSN  1e-8f

typedef __attribute__((ext_vector_type(8))) short  short8;  // 8 bf16 = 4 VGPR
typedef __attribute__((ext_vector_type(4))) float  f32x4;   // MFMA C/D

// fp32 -> bf16 round-to-nearest-even
__device__ inline unsigned short f2bf(float x) {
  unsigned int u = __builtin_bit_cast(unsigned int, x);
  unsigned int r = (u + 0x7fffu + ((u >> 16) & 1u)) >> 16;
  return (unsigned short)r;
}

// ws layout:
//   [0, 512KB)      cnk    — normalized centroids, bf16, K-chunked:
//                            cnk[(kc*N_SPK+c)*32 + (k&31)], kc = k/32
//   [512KB, +256KB) ms     — per-(block,row) softmax partials (m,s) float2
//   [768KB, +4KB)   dsum   — per-block diag-logit partial
#define CNK_BYTES ((size_t)N_SPK * DIM * 2)
#define MS_BYTES  ((size_t)1024 * N_UTT * 2 * 4)

// Kernel 1: centroid + fp32 L2-normalize -> bf16 K-chunked cnk.
// 1024 threads (2 blocks/CU x 16 waves = 32 waves/CU): the 32MB HBM read
// was latency-bound at R3's 8 waves/CU.
__global__ void centroid_kernel(const float* __restrict__ emb,
                                unsigned short* __restrict__ cnk) {
  __shared__ float4 colsum[8][128];  // 16 KB
  __shared__ float nred[2];
  int j = blockIdx.x, t = threadIdx.x;
  int c4 = t & 127, rg = t >> 7;  // c4: float4-group in row; rg: row group
  const float4* base = (const float4*)(emb + (size_t)j * N_UTT * DIM);
  float4 s = {0.f, 0.f, 0.f, 0.f};
#pragma unroll
  for (int u = 0; u < 4; ++u) {  // rows rg, rg+8, rg+16, rg+24
    float4 v = base[(rg + 8 * u) * 128 + c4];
    s.x += v.x; s.y += v.y; s.z += v.z; s.w += v.w;
  }
  colsum[rg][c4] = s;
  __syncthreads();
  if (t < 128) {
    float4 m = {0.f, 0.f, 0.f, 0.f};
#pragma unroll
    for (int g = 0; g < 8; ++g) {
      float4 v = colsum[g][t];
      m.x += v.x; m.y += v.y; m.z += v.z; m.w += v.w;
    }
    m.x *= (1.f / N_UTT); m.y *= (1.f / N_UTT);
    m.z *= (1.f / N_UTT); m.w *= (1.f / N_UTT);
    float ss = m.x * m.x + m.y * m.y + m.z * m.z + m.w * m.w;
#pragma unroll
    for (int off = 32; off > 0; off >>= 1) ss += __shfl_xor(ss, off, 64);
    if ((t & 63) == 0) nred[t >> 6] = ss;
    colsum[0][t] = m;  // stash mean for after the norm reduce
  }
  __syncthreads();
  if (t < 128) {
    float4 m = colsum[0][t];
    float inv = 1.f / fmaxf(sqrtf(nred[0] + nred[1]), EPSN);
    int d0 = t * 4, kc = d0 >> 5;
    unsigned short* p = cnk + ((size_t)kc * N_SPK + j) * 32 + (d0 & 31);
    p[0] = f2bf(m.x * inv); p[1] = f2bf(m.y * inv);
    p[2] = f2bf(m.z * inv); p[3] = f2bf(m.w * inv);
  }
}

// Kernel 2: COLUMN-SPLIT x2. block bid: speaker j = bid>>1, half h = bid&1
// (cols h*256..h*256+255). 1024 blocks x 512 threads = 4 blocks/CU x 8
// waves = 32 waves/CU — 2x R3's latency hiding at identical L2 traffic.
// A-tile (full 32x512) staged+normalized in LDS per block (R3-proven path;
// the duplicate read is L3-hot). Per-row (m,s) and diag partials to ws.
__global__ __launch_bounds__(512, 4) void ge2e_kernel(
    const float* __restrict__ emb, const unsigned short* __restrict__ cnk,
    const float* __restrict__ wp, const float* __restrict__ bp,
    float2* __restrict__ ms, float* __restrict__ dsum_g) {
  __shared__ __align__(16) unsigned short E[N_UTT * DIM];  // 32 KB
  __shared__ float red[8][N_UTT][2];                       // 2 KB (m, s)
  __shared__ float dred[8];

  int bid = blockIdx.x;
  int j = bid >> 1, h = bid & 1;
  int t = threadIdx.x;
  int lane = t & 63, wid = t >> 6;
  int n15 = lane & 15, quad = lane >> 4;

  // ---- stage + fp32 normalize + bf16 pack (R3-proven) ----
#pragma unroll
  for (int r8 = 0; r8 < 4; ++r8) {
    int r = wid * 4 + r8;
    const float* rp = emb + ((size_t)j * N_UTT + r) * DIM + lane * 8;
    float4 v0 = *(const float4*)rp;
    float4 v1 = *(const float4*)(rp + 4);
    float ss = v0.x * v0.x + v0.y * v0.y + v0.z * v0.z + v0.w * v0.w +
               v1.x * v1.x + v1.y * v1.y + v1.z * v1.z + v1.w * v1.w;
#pragma unroll
    for (int off = 32; off > 0; off >>= 1) ss += __shfl_xor(ss, off, 64);
    float inv = 1.f / fmaxf(sqrtf(ss), EPSN);
    short8 pk;
    pk[0] = (short)f2bf(v0.x * inv); pk[1] = (short)f2bf(v0.y * inv);
    pk[2] = (short)f2bf(v0.z * inv); pk[3] = (short)f2bf(v0.w * inv);
    pk[4] = (short)f2bf(v1.x * inv); pk[5] = (short)f2bf(v1.y * inv);
    pk[6] = (short)f2bf(v1.z * inv); pk[7] = (short)f2bf(v1.w * inv);
    int sw = lane ^ (r & 7);  // 16B-chunk XOR swizzle
    *(short8*)&E[r * DIM + sw * 8] = pk;
  }
  __syncthreads();

  // ---- MFMA GEMM: wave wid -> rows 0..31 x cols h*256 + wid*32 .. +31 ----
  int cbase = h * 256 + wid * 32;
  f32x4 acc[2][2];
#pragma unroll
  for (int mt = 0; mt < 2; ++mt)
#pragma unroll
    for (int nt = 0; nt < 2; ++nt) acc[mt][nt] = (f32x4){0.f, 0.f, 0.f, 0.f};

  for (int ks = 0; ks < 16; ++ks) {
    short8 b[2];
#pragma unroll
    for (int nt = 0; nt < 2; ++nt) {
      int c = cbase + nt * 16 + n15;  // B[n][k]: contiguous 1KB per 16-col run
      b[nt] = *(const short8*)(cnk + ((size_t)ks * N_SPK + c) * 32 + quad * 8);
    }
    short8 a[2];
#pragma unroll
    for (int mt = 0; mt < 2; ++mt) {
      int r = mt * 16 + n15;
      int sw = (ks * 4 + quad) ^ (r & 7);
      a[mt] = *(const short8*)&E[r * DIM + sw * 8];
    }
#pragma unroll
    for (int mt = 0; mt < 2; ++mt)
#pragma unroll
      for (int nt = 0; nt < 2; ++nt)
        acc[mt][nt] = __builtin_amdgcn_mfma_f32_16x16x32_bf16(
            a[mt], b[nt], acc[mt][nt], 0, 0, 0);
  }

  // ---- epilogue: logits = w*sim+b, per-row (m,s) over 256 cols + diag ----
  float w = *wp, bb = *bp;
  float dsum = 0.f;
#pragma unroll
  for (int mt = 0; mt < 2; ++mt)
#pragma unroll
    for (int nt = 0; nt < 2; ++nt) {
      int c = cbase + nt * 16 + n15;
      bool isdiag = (c == j);
#pragma unroll
      for (int rg = 0; rg < 4; ++rg) {
        float v = fmaf(w, acc[mt][nt][rg], bb);
        acc[mt][nt][rg] = v;
        if (isdiag) dsum += v;
      }
    }

#pragma unroll
  for (int mt = 0; mt < 2; ++mt)
#pragma unroll
    for (int rg = 0; rg < 4; ++rg) {
      float m = -INFINITY;
#pragma unroll
      for (int nt = 0; nt < 2; ++nt) m = fmaxf(m, acc[mt][nt][rg]);
#pragma unroll
      for (int off = 1; off < 16; off <<= 1) m = fmaxf(m, __shfl_xor(m, off, 64));
      float s = 0.f;
#pragma unroll
      for (int nt = 0; nt < 2; ++nt) s += __expf(acc[mt][nt][rg] - m);
#pragma unroll
      for (int off = 1; off < 16; off <<= 1) s += __shfl_xor(s, off, 64);
      if (n15 == 0) {
        int r = mt * 16 + quad * 4 + rg;
        red[wid][r][0] = m;
        red[wid][r][1] = s;
      }
    }
#pragma unroll
  for (int off = 32; off > 0; off >>= 1) dsum += __shfl_xor(dsum, off, 64);
  if (lane == 0) dred[wid] = dsum;
  __syncthreads();

  // combine 8 wave-partials per row -> (M,S) over this block's 256 cols
  if (t < 32) {
    float M = -INFINITY;
#pragma unroll
    for (int ww = 0; ww < 8; ++ww) M = fmaxf(M, red[ww][t][0]);
    float S = 0.f;
#pragma unroll
    for (int ww = 0; ww < 8; ++ww) S += red[ww][t][1] * __expf(red[ww][t][0] - M);
    ms[(size_t)bid * N_UTT + t] = make_float2(M, S);
    if (t == 0) {
      float d = dred[0] + dred[1] + dred[2] + dred[3] +
                dred[4] + dred[5] + dred[6] + dred[7];
      dsum_g[bid] = d;  // zero for the non-diag half
    }
  }
}

// Kernel 3: thread j merges the two halves' (m,s) per row, sums lse - diag.
__global__ __launch_bounds__(512) void finalize_kernel(
    const float2* __restrict__ ms, const float* __restrict__ dsum_g,
    float* __restrict__ out) {
  int t = threadIdx.x;  // speaker j = t
  const float2* m0 = ms + (size_t)(2 * t) * N_UTT;
  const float2* m1 = m0 + N_UTT;
  float acc = 0.f;
#pragma unroll 8
  for (int r = 0; r < N_UTT; ++r) {
    float2 a = m0[r], b = m1[r];
    float M = fmaxf(a.x, b.x);
    float S = a.y * __expf(a.x - M) + b.y * __expf(b.x - M);
    acc += M + __logf(S);
  }
  acc -= dsum_g[2 * t] + dsum_g[2 * t + 1];
  float v = acc;
#pragma unroll
  for (int off = 32; off > 0; off >>= 1) v += __shfl_xor(v, off, 64);
  __shared__ float r8[8];
  if ((t & 63) == 0) r8[t >> 6] = v;
  __syncthreads();
  if (t == 0) {
    float s = r8[0] + r8[1] + r8[2] + r8[3] + r8[4] + r8[5] + r8[6] + r8[7];
    out[0] = s * (1.f / (N_SPK * N_UTT));
  }
}

extern "C" void kernel_launch(void* const* d_in, const int* in_sizes, int n_in,
                              void* d_out, int out_size, void* d_ws, size_t ws_size,
                              hipStream_t stream) {
  const float* emb = (const float*)d_in[0];
  const float* wp  = (const float*)d_in[1];
  const float* bp  = (const float*)d_in[2];
  float* out = (float*)d_out;
  unsigned short* cnk = (unsigned short*)d_ws;
  float2* ms   = (float2*)((char*)d_ws + CNK_BYTES);
  float* dsum_g = (float*)((char*)d_ws + CNK_BYTES + MS_BYTES);

  centroid_kernel<<<N_SPK, 1024, 0, stream>>>(emb, cnk);
  ge2e_kernel<<<2 * N_SPK, 512, 0, stream>>>(emb, cnk, wp, bp, ms, dsum_g);
  finalize_kernel<<<1, 512, 0, stream>>>(ms, dsum_g, out);
}